// Round 4
// baseline (352.538 us; speedup 1.0000x reference)
//
#include <hip/hip_runtime.h>
#include <hip/hip_cooperative_groups.h>
#include <math.h>

namespace cg = cooperative_groups;

#define N1 10242
#define N2 40962
#define N3 163842

constexpr float SLOPE = 0.2f;
constexpr int TB = 256;

// ---- block reduce of K doubles via wave butterfly + tiny LDS combine (conflict-free) ----
template <int K>
__device__ inline void block_reduce_write(double* v, double* __restrict__ out_row,
                                          double* shred) {
#pragma unroll
    for (int m = 1; m < 64; m <<= 1) {
#pragma unroll
        for (int k = 0; k < K; ++k) v[k] += __shfl_xor(v[k], m, 64);
    }
    int lane = threadIdx.x & 63, wid = threadIdx.x >> 6;
    __syncthreads();
    if (lane < K) shred[wid * K + lane] = v[lane];
    __syncthreads();
    if (threadIdx.x < K)
        out_row[threadIdx.x] = shred[threadIdx.x] + shred[K + threadIdx.x] +
                               shred[2 * K + threadIdx.x] + shred[3 * K + threadIdx.x];
}

// ---- finalize BN stats from nb partial rows -> ss[2C] = {scale, shift} ----
template <int C>
__device__ inline void finalize_ss(const double* __restrict__ part, int nb, int n,
                                   const float* __restrict__ g, const float* __restrict__ bb,
                                   float* ss, double* red) {
    constexpr int K = 2 * C;
    constexpr int G = TB / K;
    double* tot = red + TB;
    int tid = threadIdx.x;
    double s = 0.0;
    if (tid < G * K) {
        int k = tid % K, i0 = tid / K;
        for (int i = i0; i < nb; i += G) s += part[(size_t)i * K + k];
    }
    red[tid] = s;
    __syncthreads();
    if (tid < K) {
        double t = 0.0;
        for (int j = 0; j < G; ++j) t += red[j * K + tid];
        tot[tid] = t;
    }
    __syncthreads();
    if (tid < C) {
        double mean = tot[tid] / (double)n;
        double var = tot[C + tid] / (double)n - mean * mean;
        if (var < 0.0) var = 0.0;
        float rstd = (float)(1.0 / sqrt(var + 1e-5));
        float sc = g[tid] * rstd;
        ss[tid] = sc;
        ss[C + tid] = bb[tid] - (float)mean * sc;
    }
    __syncthreads();
}

__device__ inline float yv(const float* a, const float* wsm, const float* bsm, int col) {
    return fmaf(a[0], wsm[col * 3 + 0],
           fmaf(a[1], wsm[col * 3 + 1],
           fmaf(a[2], wsm[col * 3 + 2], bsm[col])));
}

// ---- up phase: finalize stats(3) -> BN+LReLU -> 3->21 linear -> scatter -> stats(3) ----
__device__ inline void up_phase(const float* __restrict__ x, int R, int Nn,
                                const double* __restrict__ partIn, int nb, int nprev,
                                const float* __restrict__ g, const float* __restrict__ bb,
                                const float* __restrict__ w, const float* __restrict__ b,
                                const int* __restrict__ top, const int* __restrict__ down,
                                float* __restrict__ out, double* __restrict__ partOutRow,
                                float* ss, float* wsm, float* bsm, double* red, double* shred,
                                int gid, int gsz) {
    finalize_ss<3>(partIn, nb, nprev, g, bb, ss, red);
    int tid = threadIdx.x;
    if (tid < 63) wsm[tid] = w[tid];
    if (tid < 21) bsm[tid] = b[tid];
    __syncthreads();
    double v[6] = {0, 0, 0, 0, 0, 0};
    for (int i = gid; i < Nn; i += gsz) {
        float o0, o1, o2;
        if (i < R) {
            int t = top[i];
            int r = t / 7, jg = t % 7;
            float a[3];
#pragma unroll
            for (int c = 0; c < 3; ++c) {
                float u = fmaf(x[(size_t)r * 3 + c], ss[c], ss[3 + c]);
                a[c] = u >= 0.f ? u : SLOPE * u;
            }
            o0 = yv(a, wsm, bsm, jg * 3 + 0);
            o1 = yv(a, wsm, bsm, jg * 3 + 1);
            o2 = yv(a, wsm, bsm, jg * 3 + 2);
        } else {
            int k2 = i - R;
            int d0 = down[2 * k2 + 0];
            int d1 = down[2 * k2 + 1];
            int r0 = d0 / 7, j0 = d0 % 7;
            int r1 = d1 / 7, j1 = d1 % 7;
            float a0[3], a1[3];
#pragma unroll
            for (int c = 0; c < 3; ++c) {
                float u0 = fmaf(x[(size_t)r0 * 3 + c], ss[c], ss[3 + c]);
                a0[c] = u0 >= 0.f ? u0 : SLOPE * u0;
                float u1 = fmaf(x[(size_t)r1 * 3 + c], ss[c], ss[3 + c]);
                a1[c] = u1 >= 0.f ? u1 : SLOPE * u1;
            }
            float y00 = yv(a0, wsm, bsm, j0 * 3 + 0);
            float y01 = yv(a0, wsm, bsm, j0 * 3 + 1);
            float y02 = yv(a0, wsm, bsm, j0 * 3 + 2);
            float y10 = yv(a1, wsm, bsm, j1 * 3 + 0);
            float y11 = yv(a1, wsm, bsm, j1 * 3 + 1);
            float y12 = yv(a1, wsm, bsm, j1 * 3 + 2);
            // y[down].reshape(-1,3,2).mean(-1): channel-mixing across the row pair
            o0 = 0.5f * (y00 + y01);
            o1 = 0.5f * (y02 + y10);
            o2 = 0.5f * (y11 + y12);
        }
        out[(size_t)i * 3 + 0] = o0;
        out[(size_t)i * 3 + 1] = o1;
        out[(size_t)i * 3 + 2] = o2;
        v[0] += o0; v[1] += o1; v[2] += o2;
        v[3] += (double)o0 * o0; v[4] += (double)o1 * o1; v[5] += (double)o2 * o2;
    }
    block_reduce_write<6>(v, partOutRow, shred);
}

// ---- conv phase: finalize stats(CIN) -> BN+LReLU gather-7 conv -> (stats COUT) ----
template <int CIN, int COUT, bool STATS>
__device__ inline void conv_phase(const float* __restrict__ x, const int* __restrict__ neigh,
                                  const double* __restrict__ partIn, int nb, int nprev,
                                  const float* __restrict__ g, const float* __restrict__ bb,
                                  const float* __restrict__ w, const float* __restrict__ b,
                                  float* __restrict__ out, double* __restrict__ partOutRow,
                                  float* ss, float* wsm, float* bsm, double* red, double* shred,
                                  int gid, int gsz) {
    finalize_ss<CIN>(partIn, nb, nprev, g, bb, ss, red);
    int tid = threadIdx.x;
    for (int t = tid; t < COUT * 7 * CIN; t += TB) wsm[t] = w[t];
    if (tid < COUT) bsm[tid] = b[tid];
    __syncthreads();
    double v[2 * COUT];
#pragma unroll
    for (int k = 0; k < 2 * COUT; ++k) v[k] = 0.0;
    for (int i = gid; i < N3; i += gsz) {
        float acc[COUT];
#pragma unroll
        for (int o = 0; o < COUT; ++o) acc[o] = bsm[o];
#pragma unroll
        for (int j = 0; j < 7; ++j) {
            int vn = neigh[(size_t)i * 7 + j];
            float xv[CIN];
            if constexpr (CIN == 8) {
                const float4* xr = (const float4*)(x + (size_t)vn * 8);
                float4 p = xr[0], q = xr[1];
                xv[0] = p.x; xv[1] = p.y; xv[2] = p.z; xv[3] = p.w;
                xv[4] = q.x; xv[5] = q.y; xv[6] = q.z; xv[7] = q.w;
            } else {
#pragma unroll
                for (int c = 0; c < CIN; ++c) xv[c] = x[(size_t)vn * CIN + c];
            }
#pragma unroll
            for (int c = 0; c < CIN; ++c) {
                float t = fmaf(xv[c], ss[c], ss[CIN + c]);
                t = t >= 0.f ? t : SLOPE * t;
#pragma unroll
                for (int o = 0; o < COUT; ++o)
                    acc[o] = fmaf(t, wsm[o * 7 * CIN + j * CIN + c], acc[o]);
            }
        }
        if constexpr (COUT == 8) {
            float4* op = (float4*)(out + (size_t)i * 8);
            op[0] = make_float4(acc[0], acc[1], acc[2], acc[3]);
            op[1] = make_float4(acc[4], acc[5], acc[6], acc[7]);
        } else {
#pragma unroll
            for (int o = 0; o < COUT; ++o) out[(size_t)i * COUT + o] = acc[o];
        }
        if constexpr (STATS) {
#pragma unroll
            for (int o = 0; o < COUT; ++o) {
                v[o] += acc[o];
                v[COUT + o] += (double)acc[o] * acc[o];
            }
        }
    }
    if constexpr (STATS) block_reduce_write<2 * COUT>(v, partOutRow, shred);
}

struct Params {
    const float *age, *aw, *ab, *fc_w, *fc_b;
    const float *g_up0, *b_up0, *up0_w, *up0_b;
    const float *g_up1, *b_up1, *up1_w, *up1_b;
    const float *g0, *b0, *c0w, *c0b;
    const float *g1, *b1, *c1w, *c1b;
    const float *g2, *b2, *c2w, *c2b;
    const int *top0, *down0, *top1, *down1, *neigh;
    float *bufA, *bufB, *out;
    double *pP, *pQ;
};

__global__ __launch_bounds__(TB, 2) void k_all(Params P) {
    cg::grid_group gg = cg::this_grid();
    const int tid = threadIdx.x;
    const int nb = gridDim.x;
    const int gsz = nb * TB;
    const int gid = blockIdx.x * TB + tid;

    __shared__ float xs[64];
    __shared__ float ss[16];
    __shared__ float wsm[448];
    __shared__ float bsm[24];
    __shared__ double red[TB + 16];
    __shared__ double shred[64];

    // ---- phase 0: fc_age + fc -> bufA (N1,3), stats(3) -> pP ----
    if (tid < 64) xs[tid] = P.age[0] * P.aw[tid] + P.ab[tid];
    __syncthreads();
    {
        double v[6] = {0, 0, 0, 0, 0, 0};
        for (int i = gid; i < 3 * N1; i += gsz) {
            const float4* wr = (const float4*)(P.fc_w + (size_t)i * 64);
            float acc = 0.f;
#pragma unroll
            for (int q = 0; q < 16; ++q) {
                float4 w4 = wr[q];
                acc = fmaf(w4.x, xs[4 * q + 0], acc);
                acc = fmaf(w4.y, xs[4 * q + 1], acc);
                acc = fmaf(w4.z, xs[4 * q + 2], acc);
                acc = fmaf(w4.w, xs[4 * q + 3], acc);
            }
            float val = acc + P.fc_b[i];
            P.bufA[i] = val;
            double dv = (double)val, dq = dv * dv;
            int c = i % 3;  // static-index the accumulator (rule #20)
            if (c == 0)      { v[0] += dv; v[3] += dq; }
            else if (c == 1) { v[1] += dv; v[4] += dq; }
            else             { v[2] += dv; v[5] += dq; }
        }
        block_reduce_write<6>(v, P.pP + (size_t)blockIdx.x * 6, shred);
    }
    gg.sync();

    // ---- phase 1: up0 N1->N2 (bufA->bufB), stats -> pQ ----
    up_phase(P.bufA, N1, N2, P.pP, nb, N1, P.g_up0, P.b_up0, P.up0_w, P.up0_b,
             P.top0, P.down0, P.bufB, P.pQ + (size_t)blockIdx.x * 6,
             ss, wsm, bsm, red, shred, gid, gsz);
    gg.sync();

    // ---- phase 2: up1 N2->N3 (bufB->bufA), stats -> pP ----
    up_phase(P.bufB, N2, N3, P.pQ, nb, N2, P.g_up1, P.b_up1, P.up1_w, P.up1_b,
             P.top1, P.down1, P.bufA, P.pP + (size_t)blockIdx.x * 6,
             ss, wsm, bsm, red, shred, gid, gsz);
    gg.sync();

    // ---- phase 3: conv0 (N3,3)->(N3,8) (bufA->bufB), stats -> pQ ----
    conv_phase<3, 8, true>(P.bufA, P.neigh, P.pP, nb, N3, P.g0, P.b0, P.c0w, P.c0b,
                           P.bufB, P.pQ + (size_t)blockIdx.x * 16,
                           ss, wsm, bsm, red, shred, gid, gsz);
    gg.sync();

    // ---- phase 4: conv1 (N3,8)->(N3,8) (bufB->bufA), stats -> pP ----
    conv_phase<8, 8, true>(P.bufB, P.neigh, P.pQ, nb, N3, P.g1, P.b1, P.c1w, P.c1b,
                           P.bufA, P.pP + (size_t)blockIdx.x * 16,
                           ss, wsm, bsm, red, shred, gid, gsz);
    gg.sync();

    // ---- phase 5: conv2 (N3,8)->(N3,2) (bufA->out) ----
    conv_phase<8, 2, false>(P.bufA, P.neigh, P.pP, nb, N3, P.g2, P.b2, P.c2w, P.c2b,
                            P.out, nullptr, ss, wsm, bsm, red, shred, gid, gsz);
}

extern "C" void kernel_launch(void* const* d_in, const int* in_sizes, int n_in,
                              void* d_out, int out_size, void* d_ws, size_t ws_size,
                              hipStream_t stream) {
    Params P;
    P.age    = (const float*)d_in[0];
    P.aw     = (const float*)d_in[1];
    P.ab     = (const float*)d_in[2];
    P.fc_w   = (const float*)d_in[3];
    P.fc_b   = (const float*)d_in[4];
    P.g_up0  = (const float*)d_in[5];
    P.b_up0  = (const float*)d_in[6];
    P.up0_w  = (const float*)d_in[7];
    P.up0_b  = (const float*)d_in[8];
    P.g_up1  = (const float*)d_in[9];
    P.b_up1  = (const float*)d_in[10];
    P.up1_w  = (const float*)d_in[11];
    P.up1_b  = (const float*)d_in[12];
    P.g0     = (const float*)d_in[13];
    P.b0     = (const float*)d_in[14];
    P.c0w    = (const float*)d_in[15];
    P.c0b    = (const float*)d_in[16];
    P.g1     = (const float*)d_in[17];
    P.b1     = (const float*)d_in[18];
    P.c1w    = (const float*)d_in[19];
    P.c1b    = (const float*)d_in[20];
    P.g2     = (const float*)d_in[21];
    P.b2     = (const float*)d_in[22];
    P.c2w    = (const float*)d_in[23];
    P.c2b    = (const float*)d_in[24];
    P.top0   = (const int*)d_in[25];
    P.down0  = (const int*)d_in[26];
    P.top1   = (const int*)d_in[27];
    P.down1  = (const int*)d_in[28];
    P.neigh  = (const int*)d_in[29];

    float* ws = (float*)d_ws;
    P.bufA = ws;
    P.bufB = ws + (size_t)N3 * 8;
    double* dbase = (double*)((char*)d_ws + (size_t)2 * N3 * 8 * 4);
    P.pP = dbase;            // up to 1024 rows x 16 doubles
    P.pQ = dbase + 16384;
    P.out = (float*)d_out;

    int maxb = 0;
    hipOccupancyMaxActiveBlocksPerMultiprocessor(&maxb, k_all, TB, 0);
    if (maxb < 1) maxb = 1;
    long long grid_ll = (long long)maxb * 256;
    int grid = (int)(grid_ll > 1024 ? 1024 : grid_ll);

    void* args[] = {&P};
    hipLaunchCooperativeKernel((void*)k_all, dim3(grid), dim3(TB), args, 0, stream);
}

// Round 5
// 89.718 us; speedup vs baseline: 3.9294x; 3.9294x over previous
//
#include <hip/hip_runtime.h>
#include <hip/hip_fp16.h>
#include <math.h>

#define N1 10242
#define N2 40962
#define N3 163842

constexpr float SLOPE = 0.2f;
constexpr int TB = 256;

static inline int cdiv(int a, int b) { return (a + b - 1) / b; }

typedef unsigned int u32;

__device__ inline u32 packh2(float a, float b) {
    __half2 h = __floats2half2_rn(a, b);
    return *reinterpret_cast<u32*>(&h);
}
__device__ inline float2 unpackh2(u32 v) {
    __half2 h;
    *reinterpret_cast<u32*>(&h) = v;
    return __half22float2(h);
}

// ---- block reduce of K doubles via wave butterfly + tiny LDS combine (conflict-free) ----
template <int K>
__device__ void block_reduce_part(double* v, double* __restrict__ part_out, int bid) {
    __shared__ double shred[4 * K];
#pragma unroll
    for (int m = 1; m < 64; m <<= 1) {
#pragma unroll
        for (int k = 0; k < K; ++k) v[k] += __shfl_xor(v[k], m, 64);
    }
    int lane = threadIdx.x & 63, wid = threadIdx.x >> 6;
    if (lane < K) shred[wid * K + lane] = v[lane];
    __syncthreads();
    int tid = threadIdx.x;
    if (tid < K) {
        double t = shred[tid] + shred[K + tid] + shred[2 * K + tid] + shred[3 * K + tid];
        part_out[(size_t)bid * K + tid] = t;
    }
}

// ---- finalize BN stats from nb partial rows -> ss[2C] = {scale, shift} ----
template <int C>
__device__ void finalize_ss(const double* __restrict__ part, int nb, int n,
                            const float* __restrict__ g, const float* __restrict__ bb,
                            float* ss) {
    constexpr int K = 2 * C;
    constexpr int G = TB / K;
    __shared__ double red[TB];
    __shared__ double tot[K];
    int tid = threadIdx.x;
    double s = 0.0;
    if (tid < G * K) {
        int k = tid % K, i0 = tid / K;
        for (int i = i0; i < nb; i += G) s += part[(size_t)i * K + k];
    }
    red[tid] = s;
    __syncthreads();
    if (tid < K) {
        double t = 0.0;
        for (int j = 0; j < G; ++j) t += red[j * K + tid];
        tot[tid] = t;
    }
    __syncthreads();
    if (tid < C) {
        double mean = tot[tid] / (double)n;
        double var = tot[C + tid] / (double)n - mean * mean;
        if (var < 0.0) var = 0.0;
        float rstd = (float)(1.0 / sqrt(var + 1e-5));
        float sc = g[tid] * rstd;
        ss[tid] = sc;
        ss[C + tid] = bb[tid] - (float)mean * sc;
    }
    __syncthreads();
}

// ================= Kernel A: fc_age + fc -> fp32 (N1,3) + stats(3) =================
__global__ void k_fc_stats(const float* __restrict__ age,
                           const float* __restrict__ aw, const float* __restrict__ ab,
                           const float* __restrict__ w, const float* __restrict__ b,
                           float* __restrict__ out, double* __restrict__ part) {
    __shared__ float xs[64];
    int tid = threadIdx.x;
    if (tid < 64) xs[tid] = age[0] * aw[tid] + ab[tid];
    __syncthreads();
    int i = blockIdx.x * TB + tid;
    float val = 0.f;
    bool valid = i < 3 * N1;
    if (valid) {
        const float4* wr = (const float4*)(w + (size_t)i * 64);
        float acc = 0.f;
#pragma unroll
        for (int q = 0; q < 16; ++q) {
            float4 v = wr[q];
            acc = fmaf(v.x, xs[4 * q + 0], acc);
            acc = fmaf(v.y, xs[4 * q + 1], acc);
            acc = fmaf(v.z, xs[4 * q + 2], acc);
            acc = fmaf(v.w, xs[4 * q + 3], acc);
        }
        val = acc + b[i];
        out[i] = val;
    }
    double v[6] = {0, 0, 0, 0, 0, 0};
    if (valid) {
        double dv = (double)val, dq = dv * dv;
        int c = i % 3;  // static-index accumulators (rule #20)
        if (c == 0)      { v[0] = dv; v[3] = dq; }
        else if (c == 1) { v[1] = dv; v[4] = dq; }
        else             { v[2] = dv; v[5] = dq; }
    }
    block_reduce_part<6>(v, part, blockIdx.x);
}

// ================= Kernel B: BN+LReLU + 3->21 linear + scatter -> fp16 rows + stats(3) ====
__device__ inline float yv(const float* a, const float* wsm, const float* bsm, int col) {
    return fmaf(a[0], wsm[col * 3 + 0],
           fmaf(a[1], wsm[col * 3 + 1],
           fmaf(a[2], wsm[col * 3 + 2], bsm[col])));
}

template <bool SRC16>
__global__ void k_up_fused(const void* __restrict__ xsrc, int R, int Nn,
                           const double* __restrict__ part, int nb, int nprev,
                           const float* __restrict__ g, const float* __restrict__ bb,
                           const float* __restrict__ w, const float* __restrict__ b,
                           const int* __restrict__ top, const int* __restrict__ down,
                           uint2* __restrict__ out, double* __restrict__ opart) {
    __shared__ float ss[6];
    __shared__ float wsm[63], bsm[21];
    finalize_ss<3>(part, nb, nprev, g, bb, ss);
    int tid = threadIdx.x;
    if (tid < 63) wsm[tid] = w[tid];
    if (tid < 21) bsm[tid] = b[tid];
    __syncthreads();
    int i = blockIdx.x * TB + tid;
    float o0 = 0.f, o1 = 0.f, o2 = 0.f;
    bool valid = i < Nn;
    if (valid) {
        // activated-row loader: raw row r -> BN+LReLU
        auto loadact = [&](int r, float* a) {
            if constexpr (SRC16) {
                uint2 vv = ((const uint2*)xsrc)[r];
                float2 p = unpackh2(vv.x), q = unpackh2(vv.y);
                a[0] = p.x; a[1] = p.y; a[2] = q.x;
            } else {
                const float* xf = (const float*)xsrc;
                a[0] = xf[(size_t)r * 3 + 0];
                a[1] = xf[(size_t)r * 3 + 1];
                a[2] = xf[(size_t)r * 3 + 2];
            }
#pragma unroll
            for (int c = 0; c < 3; ++c) {
                float u = fmaf(a[c], ss[c], ss[3 + c]);
                a[c] = u >= 0.f ? u : SLOPE * u;
            }
        };
        if (i < R) {
            int t = top[i];
            int r = t / 7, jg = t % 7;
            float a[3];
            loadact(r, a);
            o0 = yv(a, wsm, bsm, jg * 3 + 0);
            o1 = yv(a, wsm, bsm, jg * 3 + 1);
            o2 = yv(a, wsm, bsm, jg * 3 + 2);
        } else {
            int k2 = i - R;
            int d0 = down[2 * k2 + 0];
            int d1 = down[2 * k2 + 1];
            int r0 = d0 / 7, j0 = d0 % 7;
            int r1 = d1 / 7, j1 = d1 % 7;
            float a0[3], a1[3];
            loadact(r0, a0);
            loadact(r1, a1);
            float y00 = yv(a0, wsm, bsm, j0 * 3 + 0);
            float y01 = yv(a0, wsm, bsm, j0 * 3 + 1);
            float y02 = yv(a0, wsm, bsm, j0 * 3 + 2);
            float y10 = yv(a1, wsm, bsm, j1 * 3 + 0);
            float y11 = yv(a1, wsm, bsm, j1 * 3 + 1);
            float y12 = yv(a1, wsm, bsm, j1 * 3 + 2);
            // y[down].reshape(-1,3,2).mean(-1): channel-mixing across the row pair
            o0 = 0.5f * (y00 + y01);
            o1 = 0.5f * (y02 + y10);
            o2 = 0.5f * (y11 + y12);
        }
        out[i] = make_uint2(packh2(o0, o1), packh2(o2, 0.f));
    }
    double v[6] = {0, 0, 0, 0, 0, 0};
    if (valid) {
        v[0] = (double)o0; v[1] = (double)o1; v[2] = (double)o2;
        v[3] = (double)o0 * o0; v[4] = (double)o1 * o1; v[5] = (double)o2 * o2;
    }
    block_reduce_part<6>(v, opart, blockIdx.x);
}

// ================= Kernel C: BN+LReLU + one-ring conv over fp16 rows (+ stats COUT) ======
template <int CIN, int COUT, bool STATS, bool OUT16>
__global__ void k_conv_fused(const void* __restrict__ xsrc, const int* __restrict__ neigh,
                             const double* __restrict__ part, int nb,
                             const float* __restrict__ g, const float* __restrict__ bb,
                             const float* __restrict__ w, const float* __restrict__ b,
                             void* __restrict__ outv, double* __restrict__ opart) {
    __shared__ float ss[2 * CIN];
    __shared__ float wsm[COUT * 7 * CIN];
    __shared__ float bsm[COUT];
    finalize_ss<CIN>(part, nb, N3, g, bb, ss);
    int tid = threadIdx.x;
    for (int t = tid; t < COUT * 7 * CIN; t += TB) wsm[t] = w[t];
    if (tid < COUT) bsm[tid] = b[tid];
    __syncthreads();
    int i = blockIdx.x * TB + tid;
    float acc[COUT];
#pragma unroll
    for (int o = 0; o < COUT; ++o) acc[o] = 0.f;
    bool valid = i < N3;
    if (valid) {
#pragma unroll
        for (int o = 0; o < COUT; ++o) acc[o] = bsm[o];
#pragma unroll
        for (int j = 0; j < 7; ++j) {
            int vn = neigh[(size_t)i * 7 + j];
            float xv[CIN];
            if constexpr (CIN == 3) {
                uint2 vv = ((const uint2*)xsrc)[vn];
                float2 p = unpackh2(vv.x), q = unpackh2(vv.y);
                xv[0] = p.x; xv[1] = p.y; xv[2] = q.x;
            } else {
                uint4 vv = ((const uint4*)xsrc)[vn];
                float2 p0 = unpackh2(vv.x), p1 = unpackh2(vv.y);
                float2 p2 = unpackh2(vv.z), p3 = unpackh2(vv.w);
                xv[0] = p0.x; xv[1] = p0.y; xv[2] = p1.x; xv[3] = p1.y;
                xv[4] = p2.x; xv[5] = p2.y; xv[6] = p3.x; xv[7] = p3.y;
            }
#pragma unroll
            for (int c = 0; c < CIN; ++c) {
                float t = fmaf(xv[c], ss[c], ss[CIN + c]);
                t = t >= 0.f ? t : SLOPE * t;
#pragma unroll
                for (int o = 0; o < COUT; ++o)
                    acc[o] = fmaf(t, wsm[o * 7 * CIN + j * CIN + c], acc[o]);
            }
        }
        if constexpr (OUT16) {
            uint4 ov;
            ov.x = packh2(acc[0], acc[1]);
            ov.y = packh2(acc[2], acc[3]);
            ov.z = packh2(acc[4], acc[5]);
            ov.w = packh2(acc[6], acc[7]);
            ((uint4*)outv)[i] = ov;
        } else {
            // COUT == 2, fp32 final output
            ((float2*)outv)[i] = make_float2(acc[0], acc[1]);
        }
    }
    if constexpr (STATS) {
        double v[2 * COUT];
#pragma unroll
        for (int o = 0; o < COUT; ++o) {
            double t = valid ? (double)acc[o] : 0.0;
            v[o] = t;
            v[COUT + o] = t * t;
        }
        block_reduce_part<2 * COUT>(v, opart, blockIdx.x);
    }
}

extern "C" void kernel_launch(void* const* d_in, const int* in_sizes, int n_in,
                              void* d_out, int out_size, void* d_ws, size_t ws_size,
                              hipStream_t stream) {
    const float* age      = (const float*)d_in[0];
    const float* fc_age_w = (const float*)d_in[1];
    const float* fc_age_b = (const float*)d_in[2];
    const float* fc_w     = (const float*)d_in[3];
    const float* fc_b     = (const float*)d_in[4];
    const float* bn_up0_g = (const float*)d_in[5];
    const float* bn_up0_b = (const float*)d_in[6];
    const float* up0_w    = (const float*)d_in[7];
    const float* up0_b    = (const float*)d_in[8];
    const float* bn_up1_g = (const float*)d_in[9];
    const float* bn_up1_b = (const float*)d_in[10];
    const float* up1_w    = (const float*)d_in[11];
    const float* up1_b    = (const float*)d_in[12];
    const float* bn0_g    = (const float*)d_in[13];
    const float* bn0_b    = (const float*)d_in[14];
    const float* conv0_w  = (const float*)d_in[15];
    const float* conv0_b  = (const float*)d_in[16];
    const float* bn1_g    = (const float*)d_in[17];
    const float* bn1_b    = (const float*)d_in[18];
    const float* conv1_w  = (const float*)d_in[19];
    const float* conv1_b  = (const float*)d_in[20];
    const float* bn2_g    = (const float*)d_in[21];
    const float* bn2_b    = (const float*)d_in[22];
    const float* conv2_w  = (const float*)d_in[23];
    const float* conv2_b  = (const float*)d_in[24];
    const int* up_top0    = (const int*)d_in[25];
    const int* up_down0   = (const int*)d_in[26];
    const int* up_top1    = (const int*)d_in[27];
    const int* up_down1   = (const int*)d_in[28];
    const int* neigh      = (const int*)d_in[29];

    // workspace layout (byte offsets, all 16B-aligned)
    char* base = (char*)d_ws;
    float* bufA = (float*)base;                        // (N1,3) fp32: 122,904 B
    uint2* up0o = (uint2*)(base + 0x020000);           // (N2)   4h rows: 327,696 B
    uint2* up1o = (uint2*)(base + 0x080000);           // (N3)   4h rows: 1,310,736 B
    uint4* c0o  = (uint4*)(base + 0x200000);           // (N3)   8h rows: 2,621,472 B
    uint4* c1o  = (uint4*)(base + 0x500000);           // (N3)   8h rows: 2,621,472 B
    double* dbase  = (double*)(base + 0x800000);
    double* partA  = dbase;                 // 121*6
    double* partB0 = partA + 1024;          // 161*6
    double* partB1 = partB0 + 1024;         // 641*6
    double* partC0 = partB1 + 4096;         // 641*16
    double* partC1 = partC0 + 10752;        // 641*16

    const int nbA  = cdiv(3 * N1, TB);  // 121
    const int nbB0 = cdiv(N2, TB);      // 161
    const int nbB1 = cdiv(N3, TB);      // 641
    const int nbC  = cdiv(N3, TB);      // 641

    // 1) fc_age + fc -> bufA (N1,3) fp32, stats -> partA
    k_fc_stats<<<nbA, TB, 0, stream>>>(age, fc_age_w, fc_age_b, fc_w, fc_b, bufA, partA);

    // 2) up0: N1 -> N2 (fp32 -> fp16 rows), finalize partA, emit partB0
    k_up_fused<false><<<nbB0, TB, 0, stream>>>(bufA, N1, N2, partA, nbA, N1,
                                               bn_up0_g, bn_up0_b, up0_w, up0_b,
                                               up_top0, up_down0, up0o, partB0);

    // 3) up1: N2 -> N3 (fp16 -> fp16 rows), finalize partB0, emit partB1
    k_up_fused<true><<<nbB1, TB, 0, stream>>>(up0o, N2, N3, partB0, nbB0, N2,
                                              bn_up1_g, bn_up1_b, up1_w, up1_b,
                                              up_top1, up_down1, up1o, partB1);

    // 4) conv0: (N3,3)h -> (N3,8)h, finalize partB1, emit partC0
    k_conv_fused<3, 8, true, true><<<nbC, TB, 0, stream>>>(up1o, neigh, partB1, nbB1,
                                                           bn0_g, bn0_b, conv0_w, conv0_b,
                                                           c0o, partC0);

    // 5) conv1: (N3,8)h -> (N3,8)h, finalize partC0, emit partC1
    k_conv_fused<8, 8, true, true><<<nbC, TB, 0, stream>>>(c0o, neigh, partC0, nbC,
                                                           bn1_g, bn1_b, conv1_w, conv1_b,
                                                           c1o, partC1);

    // 6) conv2: (N3,8)h -> (N3,2) fp32 d_out, finalize partC1
    k_conv_fused<8, 2, false, false><<<nbC, TB, 0, stream>>>(c1o, neigh, partC1, nbC,
                                                             bn2_g, bn2_b, conv2_w, conv2_b,
                                                             (float*)d_out, nullptr);
}